// Round 3
// baseline (3040.887 us; speedup 1.0000x reference)
//
#include <hip/hip_runtime.h>
#include <math.h>

#define NQ 10
#define NL 4

// ---- 1q complex gate on a register-bit qubit (pure FMA, no cross-lane)
template<int RB>
__device__ __forceinline__ void gate_rbit(float ar[16], float ai[16],
    float u00r, float u00i, float u01r, float u01i,
    float u10r, float u10i, float u11r, float u11i) {
#pragma unroll
  for (int r0 = 0; r0 < 16; ++r0) {
    if ((r0 >> RB) & 1) continue;
    const int r1 = r0 | (1 << RB);
    const float a0r = ar[r0], a0i = ai[r0];
    const float a1r = ar[r1], a1i = ai[r1];
    ar[r0] = u00r * a0r - u00i * a0i + u01r * a1r - u01i * a1i;
    ai[r0] = u00r * a0i + u00i * a0r + u01r * a1i + u01i * a1r;
    ar[r1] = u10r * a0r - u10i * a0i + u11r * a1r - u11i * a1i;
    ai[r1] = u10r * a0i + u10i * a0r + u11r * a1i + u11i * a1r;
  }
}

// ---- 1q complex gate on lane-bit LB: two 8-register batches
// (fetch 16 partners, then FMA) to bound live temps while keeping a
// full latency-hiding batch of independent shuffles.
template<int LB>
__device__ __forceinline__ void gate_lbit(float ar[16], float ai[16],
    float cSr, float cSi, float cPr, float cPi) {
#pragma unroll
  for (int h = 0; h < 2; ++h) {
    float pr[8], pi[8];
#pragma unroll
    for (int k = 0; k < 8; ++k) {
      pr[k] = __shfl_xor(ar[h * 8 + k], 1 << LB, 64);
      pi[k] = __shfl_xor(ai[h * 8 + k], 1 << LB, 64);
    }
#pragma unroll
    for (int k = 0; k < 8; ++k) {
      const int r = h * 8 + k;
      const float sr = ar[r], si = ai[r];
      ar[r] = cSr * sr - cSi * si + cPr * pr[k] - cPi * pi[k];
      ai[r] = cSr * si + cSi * sr + cPr * pi[k] + cPi * pr[k];
    }
  }
}

// ---- whole CNOT ring as ONE linear permutation (HW-verified in R2):
// dst[r'][lane'] = src[gray4(r') ^ ((lane'&1)*12)][(lane'^(lane'>>1)) ^ ((r'&1)<<5)]
__device__ __forceinline__ void ring_comp(float a[16], int addr0, int addr1, bool odd) {
  float B[16];
#pragma unroll
  for (int g = 0; g < 16; ++g) {
    const int par = ((g ^ (g >> 1) ^ (g >> 2) ^ (g >> 3)) & 1);
    B[g] = __int_as_float(__builtin_amdgcn_ds_bpermute(par ? addr1 : addr0,
                                                       __float_as_int(a[g])));
  }
#pragma unroll
  for (int r = 0; r < 16; ++r) {
    const int g = (r ^ (r >> 1));
    a[r] = odd ? B[g ^ 12] : B[g];
  }
}

__global__ __launch_bounds__(256, 8) void qsim_kernel(const float* __restrict__ x,
                                                      const float* __restrict__ w,
                                                      float* __restrict__ out,
                                                      int batch) {
  // ---- per-block: the 40 shared Rot matrices into LDS
  __shared__ float gsh[NL * NQ * 8];
  const int tid = threadIdx.x;
  if (tid < NL * NQ) {
    const float phi = w[tid * 3 + 0];
    const float th  = w[tid * 3 + 1];
    const float om  = w[tid * 3 + 2];
    float c, s, cp, sp, cm, sm;
    sincosf(0.5f * th, &s, &c);
    sincosf(-0.5f * (phi + om), &sp, &cp);
    sincosf(0.5f * (phi - om), &sm, &cm);
    float* g = &gsh[tid * 8];
    g[0] = cp * c;  g[1] = sp * c;
    g[2] = -cm * s; g[3] = -sm * s;
    g[4] = cm * s;  g[5] = -sm * s;
    g[6] = cp * c;  g[7] = -sp * c;
  }
  __syncthreads();

  const int samp = (int)(blockIdx.x * (blockDim.x >> 6)) + (tid >> 6);
  const int lane = tid & 63;
  if (samp >= batch) return;

  const int addr0 = 4 * (lane ^ (lane >> 1));
  const int addr1 = addr0 ^ 128;
  const bool lodd = (lane & 1);

  // ---- encoding: product state, built with minimal live registers.
  const float* xb = x + samp * NQ;
  // lane-bit factor first (2 live regs), qubits 9..4 <-> lane bits 0..5
  float lfac;
  {
    float c, s;
    sincosf(0.5f * xb[9], &s, &c); lfac  = ((lane >> 0) & 1) ? s : c;
    sincosf(0.5f * xb[8], &s, &c); lfac *= ((lane >> 1) & 1) ? s : c;
    sincosf(0.5f * xb[7], &s, &c); lfac *= ((lane >> 2) & 1) ? s : c;
    sincosf(0.5f * xb[6], &s, &c); lfac *= ((lane >> 3) & 1) ? s : c;
    sincosf(0.5f * xb[5], &s, &c); lfac *= ((lane >> 4) & 1) ? s : c;
    sincosf(0.5f * xb[4], &s, &c); lfac *= ((lane >> 5) & 1) ? s : c;
  }
  float c0, s0, c1, s1, c2, s2, c3, s3;
  sincosf(0.5f * xb[0], &s0, &c0);
  sincosf(0.5f * xb[1], &s1, &c1);
  sincosf(0.5f * xb[2], &s2, &c2);
  sincosf(0.5f * xb[3], &s3, &c3);

  float ar[16], ai[16];
#pragma unroll
  for (int r = 0; r < 16; ++r) {
    float f = lfac;                     // r bit rb <-> qubit 3-rb
    f *= ((r >> 0) & 1) ? s3 : c3;
    f *= ((r >> 1) & 1) ? s2 : c2;
    f *= ((r >> 2) & 1) ? s1 : c1;
    f *= ((r >> 3) & 1) ? s0 : c0;
    ar[r] = f;
    ai[r] = 0.f;
  }

  // ---- layers
#pragma unroll
  for (int l = 0; l < NL; ++l) {
    const float* gl = &gsh[l * NQ * 8];

    // qubits 0..3: register-bit gates
#pragma unroll
    for (int q = 0; q < 4; ++q) {
      const float* g = gl + q * 8;
      const float u00r = g[0], u00i = g[1], u01r = g[2], u01i = g[3];
      const float u10r = g[4], u10i = g[5], u11r = g[6], u11i = g[7];
      if (q == 0)      gate_rbit<3>(ar, ai, u00r,u00i,u01r,u01i,u10r,u10i,u11r,u11i);
      else if (q == 1) gate_rbit<2>(ar, ai, u00r,u00i,u01r,u01i,u10r,u10i,u11r,u11i);
      else if (q == 2) gate_rbit<1>(ar, ai, u00r,u00i,u01r,u01i,u10r,u10i,u11r,u11i);
      else             gate_rbit<0>(ar, ai, u00r,u00i,u01r,u01i,u10r,u10i,u11r,u11i);
    }
    // qubits 4..9: lane-bit gates (lane bit 9-q); coefficients selected per lane once
#pragma unroll
    for (int q = 4; q < 10; ++q) {
      const float* g = gl + q * 8;
      const bool hb = (lane >> (9 - q)) & 1;
      const float cSr = hb ? g[6] : g[0];
      const float cSi = hb ? g[7] : g[1];
      const float cPr = hb ? g[4] : g[2];
      const float cPi = hb ? g[5] : g[3];
      if (q == 4)      gate_lbit<5>(ar, ai, cSr, cSi, cPr, cPi);
      else if (q == 5) gate_lbit<4>(ar, ai, cSr, cSi, cPr, cPi);
      else if (q == 6) gate_lbit<3>(ar, ai, cSr, cSi, cPr, cPi);
      else if (q == 7) gate_lbit<2>(ar, ai, cSr, cSi, cPr, cPi);
      else if (q == 8) gate_lbit<1>(ar, ai, cSr, cSi, cPr, cPi);
      else             gate_lbit<0>(ar, ai, cSr, cSi, cPr, cPi);
    }

    // entire CNOT ring as one permutation (one latency batch per component)
    ring_comp(ar, addr0, addr1, lodd);
    ring_comp(ai, addr0, addr1, lodd);
  }

  // ---- measurement
  float p[16];
#pragma unroll
  for (int r = 0; r < 16; ++r) p[r] = ar[r] * ar[r] + ai[r] * ai[r];

  float z[NQ];
#pragma unroll
  for (int q = 0; q < 4; ++q) {
    const int rb = 3 - q;
    float acc = 0.f;
#pragma unroll
    for (int r = 0; r < 16; ++r) acc += ((r >> rb) & 1) ? -p[r] : p[r];
    z[q] = acc;
  }
  float P = 0.f;
#pragma unroll
  for (int r = 0; r < 16; ++r) P += p[r];
#pragma unroll
  for (int q = 4; q < NQ; ++q) {
    const int lb = 9 - q;
    z[q] = ((lane >> lb) & 1) ? -P : P;
  }

#pragma unroll
  for (int q = 0; q < NQ; ++q) {
    float v = z[q];
#pragma unroll
    for (int m = 1; m < 64; m <<= 1) v += __shfl_xor(v, m, 64);
    z[q] = v;
  }

  if (lane == 0) {
#pragma unroll
    for (int q = 0; q < NQ; ++q) out[samp * NQ + q] = z[q];
  }
}

extern "C" void kernel_launch(void* const* d_in, const int* in_sizes, int n_in,
                              void* d_out, int out_size, void* d_ws, size_t ws_size,
                              hipStream_t stream) {
  const float* x = (const float*)d_in[0];
  const float* w = (const float*)d_in[1];
  float* out = (float*)d_out;
  const int batch = in_sizes[0] / NQ;
  const int waves_per_block = 256 / 64;
  const int grid = (batch + waves_per_block - 1) / waves_per_block;
  hipLaunchKernelGGL(qsim_kernel, dim3(grid), dim3(256), 0, stream, x, w, out, batch);
}

// Round 4
// 150.457 us; speedup vs baseline: 20.2110x; 20.2110x over previous
//
#include <hip/hip_runtime.h>
#include <math.h>

#define NQ 10
#define NL 4

typedef float v2f __attribute__((ext_vector_type(2)));

// ---------- packed complex arithmetic (VOP3P, 2 floats per instruction) ----------
// d = u * a (complex):  d = (ur*re - ui*im, ur*im + ui*re)
__device__ __forceinline__ v2f cmul(v2f u, v2f a) {
  v2f d;
  asm("v_pk_mul_f32 %0, %1, %2 op_sel_hi:[0,1]\n\t"
      "v_pk_fma_f32 %0, %1, %2, %0 op_sel:[1,1,0] op_sel_hi:[1,0,1] neg_lo:[0,1,0]"
      : "=&v"(d) : "v"(u), "v"(a));
  return d;
}
// d += u * a (complex)
__device__ __forceinline__ void cfma(v2f &d, v2f u, v2f a) {
  asm("v_pk_fma_f32 %0, %1, %2, %0 op_sel_hi:[0,1,1]\n\t"
      "v_pk_fma_f32 %0, %1, %2, %0 op_sel:[1,1,0] op_sel_hi:[1,0,1] neg_lo:[0,1,0]"
      : "+v"(d) : "v"(u), "v"(a));
}

// ---------- gates ----------
// 1q gate on a register-bit qubit: pure packed FMA, no cross-lane
template<int RB>
__device__ __forceinline__ void gate_rbit(v2f a[16], v2f u00, v2f u01, v2f u10, v2f u11) {
#pragma unroll
  for (int r0 = 0; r0 < 16; ++r0) {
    if ((r0 >> RB) & 1) continue;
    const int r1 = r0 | (1 << RB);
    const v2f a0 = a[r0], a1 = a[r1];
    v2f n0 = cmul(u00, a0); cfma(n0, u01, a1);
    v2f n1 = cmul(u10, a0); cfma(n1, u11, a1);
    a[r0] = n0;
    a[r1] = n1;
  }
}

// 1q gate on lane-bit LB: batches of 4 regs (8 independent shuffles, then packed FMA).
// cS = (hi ? u11 : u00), cP = (hi ? u10 : u01), selected once per gate by caller.
template<int LB>
__device__ __forceinline__ void gate_lbit(v2f a[16], v2f cS, v2f cP) {
#pragma unroll
  for (int h = 0; h < 4; ++h) {
    v2f p[4];
#pragma unroll
    for (int k = 0; k < 4; ++k) {
      p[k].x = __shfl_xor(a[h * 4 + k].x, 1 << LB, 64);
      p[k].y = __shfl_xor(a[h * 4 + k].y, 1 << LB, 64);
    }
#pragma unroll
    for (int k = 0; k < 4; ++k) {
      const int r = h * 4 + k;
      v2f n = cmul(cS, a[r]); cfma(n, cP, p[k]);
      a[r] = n;
    }
  }
}

// ---------- whole CNOT ring as ONE linear permutation (HW-verified R2/R3):
// dst[r'][lane'] = src[gray4(r') ^ ((lane'&1)*12)][(lane'^(lane'>>1)) ^ ((r'&1)<<5)]
__device__ __forceinline__ void ring_comp(v2f a[16], int addr0, int addr1, bool odd) {
  float B[16];
#pragma unroll
  for (int g = 0; g < 16; ++g) {
    const int par = ((g ^ (g >> 1) ^ (g >> 2) ^ (g >> 3)) & 1);
    B[g] = __int_as_float(__builtin_amdgcn_ds_bpermute(par ? addr1 : addr0,
                                                       __float_as_int(a[g].x)));
  }
#pragma unroll
  for (int r = 0; r < 16; ++r) {
    const int g = (r ^ (r >> 1));
    a[r].x = odd ? B[g ^ 12] : B[g];
  }
#pragma unroll
  for (int g = 0; g < 16; ++g) {
    const int par = ((g ^ (g >> 1) ^ (g >> 2) ^ (g >> 3)) & 1);
    B[g] = __int_as_float(__builtin_amdgcn_ds_bpermute(par ? addr1 : addr0,
                                                       __float_as_int(a[g].y)));
  }
#pragma unroll
  for (int r = 0; r < 16; ++r) {
    const int g = (r ^ (r >> 1));
    a[r].y = odd ? B[g ^ 12] : B[g];
  }
}

__global__ __launch_bounds__(256) void qsim_kernel(const float* __restrict__ x,
                                                   const float* __restrict__ w,
                                                   float* __restrict__ out,
                                                   int batch) {
  // ---- per-block: the 40 shared Rot matrices into LDS
  __shared__ float gsh[NL * NQ * 8];
  const int tid = threadIdx.x;
  if (tid < NL * NQ) {
    const float phi = w[tid * 3 + 0];
    const float th  = w[tid * 3 + 1];
    const float om  = w[tid * 3 + 2];
    float c, s, cp, sp, cm, sm;
    sincosf(0.5f * th, &s, &c);
    sincosf(-0.5f * (phi + om), &sp, &cp);
    sincosf(0.5f * (phi - om), &sm, &cm);
    float* g = &gsh[tid * 8];
    g[0] = cp * c;  g[1] = sp * c;
    g[2] = -cm * s; g[3] = -sm * s;
    g[4] = cm * s;  g[5] = -sm * s;
    g[6] = cp * c;  g[7] = -sp * c;
  }
  __syncthreads();

  const int samp = (int)(blockIdx.x * (blockDim.x >> 6)) + (tid >> 6);
  const int lane = tid & 63;
  if (samp >= batch) return;

  const int addr0 = 4 * (lane ^ (lane >> 1));
  const int addr1 = addr0 ^ 128;
  const bool lodd = (lane & 1);

  // ---- encoding: product state, minimal live registers
  const float* xb = x + samp * NQ;
  float lfac;
  {
    float c, s;
    sincosf(0.5f * xb[9], &s, &c); lfac  = ((lane >> 0) & 1) ? s : c;
    sincosf(0.5f * xb[8], &s, &c); lfac *= ((lane >> 1) & 1) ? s : c;
    sincosf(0.5f * xb[7], &s, &c); lfac *= ((lane >> 2) & 1) ? s : c;
    sincosf(0.5f * xb[6], &s, &c); lfac *= ((lane >> 3) & 1) ? s : c;
    sincosf(0.5f * xb[5], &s, &c); lfac *= ((lane >> 4) & 1) ? s : c;
    sincosf(0.5f * xb[4], &s, &c); lfac *= ((lane >> 5) & 1) ? s : c;
  }
  float c0, s0, c1, s1, c2, s2, c3, s3;
  sincosf(0.5f * xb[0], &s0, &c0);
  sincosf(0.5f * xb[1], &s1, &c1);
  sincosf(0.5f * xb[2], &s2, &c2);
  sincosf(0.5f * xb[3], &s3, &c3);

  v2f a[16];
#pragma unroll
  for (int r = 0; r < 16; ++r) {
    float f = lfac;                     // r bit rb <-> qubit 3-rb
    f *= ((r >> 0) & 1) ? s3 : c3;
    f *= ((r >> 1) & 1) ? s2 : c2;
    f *= ((r >> 2) & 1) ? s1 : c1;
    f *= ((r >> 3) & 1) ? s0 : c0;
    a[r].x = f;
    a[r].y = 0.f;
  }

  // ---- layers
#pragma unroll
  for (int l = 0; l < NL; ++l) {
    const float* gl = &gsh[l * NQ * 8];

    // qubits 0..3: register-bit gates (packed FMA only)
#pragma unroll
    for (int q = 0; q < 4; ++q) {
      const v2f* gv = (const v2f*)(gl + q * 8);
      const v2f u00 = gv[0], u01 = gv[1], u10 = gv[2], u11 = gv[3];
      if (q == 0)      gate_rbit<3>(a, u00, u01, u10, u11);
      else if (q == 1) gate_rbit<2>(a, u00, u01, u10, u11);
      else if (q == 2) gate_rbit<1>(a, u00, u01, u10, u11);
      else             gate_rbit<0>(a, u00, u01, u10, u11);
    }
    // qubits 4..9: lane-bit gates (lane bit 9-q)
#pragma unroll
    for (int q = 4; q < 10; ++q) {
      const v2f* gv = (const v2f*)(gl + q * 8);
      const bool hb = (lane >> (9 - q)) & 1;
      const v2f cS = hb ? gv[3] : gv[0];
      const v2f cP = hb ? gv[2] : gv[1];
      if (q == 4)      gate_lbit<5>(a, cS, cP);
      else if (q == 5) gate_lbit<4>(a, cS, cP);
      else if (q == 6) gate_lbit<3>(a, cS, cP);
      else if (q == 7) gate_lbit<2>(a, cS, cP);
      else if (q == 8) gate_lbit<1>(a, cS, cP);
      else             gate_lbit<0>(a, cS, cP);
    }

    // entire CNOT ring as one permutation
    ring_comp(a, addr0, addr1, lodd);
  }

  // ---- measurement
  float p[16];
#pragma unroll
  for (int r = 0; r < 16; ++r) p[r] = a[r].x * a[r].x + a[r].y * a[r].y;

  float z[NQ];
#pragma unroll
  for (int q = 0; q < 4; ++q) {
    const int rb = 3 - q;
    float acc = 0.f;
#pragma unroll
    for (int r = 0; r < 16; ++r) acc += ((r >> rb) & 1) ? -p[r] : p[r];
    z[q] = acc;
  }
  float P = 0.f;
#pragma unroll
  for (int r = 0; r < 16; ++r) P += p[r];
#pragma unroll
  for (int q = 4; q < NQ; ++q) {
    const int lb = 9 - q;
    z[q] = ((lane >> lb) & 1) ? -P : P;
  }

#pragma unroll
  for (int q = 0; q < NQ; ++q) {
    float v = z[q];
#pragma unroll
    for (int m = 1; m < 64; m <<= 1) v += __shfl_xor(v, m, 64);
    z[q] = v;
  }

  if (lane == 0) {
#pragma unroll
    for (int q = 0; q < NQ; ++q) out[samp * NQ + q] = z[q];
  }
}

extern "C" void kernel_launch(void* const* d_in, const int* in_sizes, int n_in,
                              void* d_out, int out_size, void* d_ws, size_t ws_size,
                              hipStream_t stream) {
  const float* x = (const float*)d_in[0];
  const float* w = (const float*)d_in[1];
  float* out = (float*)d_out;
  const int batch = in_sizes[0] / NQ;
  const int waves_per_block = 256 / 64;
  const int grid = (batch + waves_per_block - 1) / waves_per_block;
  hipLaunchKernelGGL(qsim_kernel, dim3(grid), dim3(256), 0, stream, x, w, out, batch);
}